// Round 3
// baseline (1124.555 us; speedup 1.0000x reference)
//
#include <hip/hip_runtime.h>
#include <cstdint>
#include <cstddef>

// FraudDetector hetero-GAT on MI355X.
// R11: (a) unified gemm_pipe (projections + G-GEMMs): 64x128 tile, 4 waves
//      2x2, BK=32, LDS double-buffer (ONE barrier/iter), prefetch depth 2
//      (two static register sets), rows padded to 40 ushorts (80B stride,
//      2-way bank aliasing = free). (b) aggG2: half-wave per (dst,rel) --
//      32 lanes hold all 128 channels, lane-local den/acc (no cross-lane
//      shuffles), 8 edges in flight, wave covers 2 dsts.
#define N_USER 100000
#define N_POST 50000
#define TEXT_D 768
#define USER_D 64
#define E_TOT 1450000   // pub+rep+int+fol (entity path is dead code)
#define N_TOT 300000    // 50k+50k+100k+100k concatenated dst spaces

typedef unsigned short ushort_t;
typedef float f4v __attribute__((ext_vector_type(4)));
typedef short s8v __attribute__((ext_vector_type(8)));
typedef unsigned short u4v __attribute__((ext_vector_type(4)));
typedef unsigned short u8v __attribute__((ext_vector_type(8)));

__device__ __forceinline__ float leaky(float v) { return v > 0.f ? v : 0.2f * v; }
__device__ __forceinline__ void split_bf(float x, ushort_t& hi, ushort_t& lo) {
  unsigned u = __float_as_uint(x);
  hi = (ushort_t)(u >> 16);
  float r = x - __uint_as_float(u & 0xFFFF0000u);
  lo = (ushort_t)(__float_as_uint(r) >> 16);
}

struct Ptrs4 { const int* p[4]; };

// ---------------------------------------------------------------------------
// wvec: wv[(lr*2+h)*128+k] = sum_c W[lr][k][h*128+c] * a[lr][h][c]
__global__ void wvec_kernel(const float* __restrict__ W, const float* __restrict__ av,
                            float* __restrict__ wv) {
  int b = blockIdx.x;              // 20 = lr(10) * h(2)
  int lr = b / 2, h = b % 2;
  const float* Wp = W + ((size_t)lr * 128 * 256) + (size_t)threadIdx.x * 256 + h * 128;
  const float* ap = av + (size_t)(lr * 2 + h) * 128;
  float acc = 0.f;
  for (int c = 0; c < 128; ++c) acc += Wp[c] * ap[c];
  wv[(size_t)(lr * 2 + h) * 128 + threadIdx.x] = acc;
}

// ---------------------------------------------------------------------------
// wt_prep: WT{h,l}[c][k] = split(W[k][c]).   (projection weights)
__global__ void wt_prep(const float* __restrict__ W, ushort_t* __restrict__ WTh,
                        ushort_t* __restrict__ WTl, int K, int C) {
  int k = blockIdx.x * 256 + threadIdx.x;
  int c = blockIdx.y;
  if (k >= K) return;
  ushort_t h, l;
  split_bf(W[(size_t)k * C + c], h, l);
  WTh[(size_t)c * K + k] = h;
  WTl[(size_t)c * K + k] = l;
}

// stk_prep: stacked src-weight for the G-GEMM. kk = rel*256 + h*128 + j;
// ST{h,l}[c][kk] = split(Wrel[j][h*128+c]).  grid (2, 128), block 256.
__global__ void stk_prep(const float* __restrict__ Wa, const float* __restrict__ Wb,
                         ushort_t* __restrict__ STh, ushort_t* __restrict__ STl) {
  int rel = blockIdx.x;
  int c = blockIdx.y;
  int t = threadIdx.x;         // h*128 + j
  const float* W = rel ? Wb : Wa;
  float v = W[(size_t)(t & 127) * 256 + (size_t)(t >> 7) * 128 + c];
  ushort_t hh, ll;
  split_bf(v, hh, ll);
  size_t idx = (size_t)c * 512 + (size_t)rel * 256 + t;
  STh[idx] = hh;
  STl[idx] = ll;
}

// combined per-dst-space biases: BS[0]=l0 pub+rep, BS[1]=l0 int+fol, BS[2]=l1 pub+rep
__global__ void bias_sum(const float* __restrict__ gbias, float* __restrict__ BS) {
  int c = threadIdx.x;  // 128
  BS[c]       = gbias[0 * 640 + 0 * 128 + c] + gbias[0 * 640 + 1 * 128 + c];
  BS[128 + c] = gbias[0 * 640 + 3 * 128 + c] + gbias[0 * 640 + 4 * 128 + c];
  BS[256 + c] = gbias[1 * 640 + 0 * 128 + c] + gbias[1 * 640 + 1 * 128 + c];
}

// ---------------------------------------------------------------------------
// gemm_pipe: Out[N][128] = (A)[N][K] @ (Bh+Bl)[128][K]^T (+bias, opt relu).
// A either f32 (ASPLIT=false: split to bf16 hi/lo in-kernel) or pre-split
// bf16 pair (ASPLIT=true).  Tile 64x128, 4 waves 2x2 (32x64 each), BK=32.
// LDS double-buffered (one barrier per K-step), 80B row stride (2-way banks).
// Prefetch depth 2: global loads issued 2 iterations before LDS write.
template <bool ASPLIT, bool RELU>
__global__ __launch_bounds__(256) void gemm_pipe(const void* __restrict__ Ag,
                                                 const ushort_t* __restrict__ Agl,
                                                 const ushort_t* __restrict__ Bgh,
                                                 const ushort_t* __restrict__ Bgl,
                                                 const float* __restrict__ bv,
                                                 float* __restrict__ Out,
                                                 int N, int K) {
  __shared__ ushort_t LAh[2][64 * 40], LAl[2][64 * 40];
  __shared__ ushort_t LBh[2][128 * 40], LBl[2][128 * 40];
  int t = threadIdx.x;
  int lane = t & 63, w = t >> 6;
  int m = lane & 15, quad = lane >> 4;
  int wr = w >> 1, wc = w & 1;
  int row0 = blockIdx.x * 64;
  int nkb = K >> 5;

  const float* Xf = (const float*)Ag;
  const ushort_t* Xh = (const ushort_t*)Ag;

  // staging coordinates
  int arf[2], af4[2];            // f32-A: 2 float4/thread (r=p>>3, f4=p&7)
  int ars = 0, ags = 0;          // split-A: 1 u8v/thread/half (r=t>>2, g=t&3)
  if (!ASPLIT) {
#pragma unroll
    for (int i = 0; i < 2; ++i) {
      int p = t + 256 * i;
      int r = p >> 3;
      int row = row0 + r;
      arf[i] = (row < N) ? row : (N - 1);
      af4[i] = p & 7;
    }
  } else {
    int r = t >> 2;
    int row = row0 + r;
    ars = (row < N) ? row : (N - 1);
    ags = t & 3;
  }
  int bc_[2], bg_[2];            // B: 2 u8v/thread/half (c=p>>2, g=p&3)
#pragma unroll
  for (int i = 0; i < 2; ++i) {
    int p = t + 256 * i;
    bc_[i] = p >> 2;
    bg_[i] = p & 3;
  }

  f4v acc[2][4];
#pragma unroll
  for (int mt = 0; mt < 2; ++mt)
#pragma unroll
    for (int ct = 0; ct < 4; ++ct) acc[mt][ct] = (f4v){0.f, 0.f, 0.f, 0.f};

  // two static prefetch register sets (set index == LDS buf index)
  float4 pa0[2], pa1[2];
  u8v pah0, pal0, pah1, pal1;
  u8v pbh0[2], pbl0[2], pbh1[2], pbl1[2];

#define LOADG(S, KB)                                                          \
  do {                                                                        \
    int k0 = (KB) * 32;                                                       \
    if (ASPLIT) {                                                             \
      pah##S = *(const u8v*)(Xh + (size_t)ars * K + k0 + ags * 8);            \
      pal##S = *(const u8v*)(Agl + (size_t)ars * K + k0 + ags * 8);           \
    } else {                                                                  \
      _Pragma("unroll")                                                       \
      for (int i = 0; i < 2; ++i)                                             \
        pa##S[i] = *(const float4*)(Xf + (size_t)arf[i] * K + k0 + af4[i] * 4);\
    }                                                                         \
    _Pragma("unroll")                                                         \
    for (int i = 0; i < 2; ++i) {                                             \
      pbh##S[i] = *(const u8v*)(Bgh + (size_t)bc_[i] * K + k0 + bg_[i] * 8);  \
      pbl##S[i] = *(const u8v*)(Bgl + (size_t)bc_[i] * K + k0 + bg_[i] * 8);  \
    }                                                                         \
  } while (0)

#define WRITES(S)                                                             \
  do {                                                                        \
    if (ASPLIT) {                                                             \
      int r = t >> 2, g = t & 3;                                              \
      *(u8v*)&LAh[S][r * 40 + g * 8] = pah##S;                                \
      *(u8v*)&LAl[S][r * 40 + g * 8] = pal##S;                                \
    } else {                                                                  \
      _Pragma("unroll")                                                       \
      for (int i = 0; i < 2; ++i) {                                           \
        int p = t + 256 * i;                                                  \
        int r = p >> 3, f4i = p & 7;                                          \
        u4v hh, ll;                                                           \
        ushort_t sh, sl;                                                      \
        split_bf(pa##S[i].x, sh, sl); hh[0] = sh; ll[0] = sl;                 \
        split_bf(pa##S[i].y, sh, sl); hh[1] = sh; ll[1] = sl;                 \
        split_bf(pa##S[i].z, sh, sl); hh[2] = sh; ll[2] = sl;                 \
        split_bf(pa##S[i].w, sh, sl); hh[3] = sh; ll[3] = sl;                 \
        *(u4v*)&LAh[S][r * 40 + f4i * 4] = hh;                                \
        *(u4v*)&LAl[S][r * 40 + f4i * 4] = ll;                                \
      }                                                                       \
    }                                                                         \
    _Pragma("unroll")                                                         \
    for (int i = 0; i < 2; ++i) {                                             \
      int c = bc_[i], g = bg_[i];                                             \
      *(u8v*)&LBh[S][c * 40 + g * 8] = pbh##S[i];                             \
      *(u8v*)&LBl[S][c * 40 + g * 8] = pbl##S[i];                             \
    }                                                                         \
  } while (0)

  auto MF = [&](int buf) {
    s8v ah[2], al2[2];
#pragma unroll
    for (int mt = 0; mt < 2; ++mt) {
      int r = wr * 32 + mt * 16 + m;
      ah[mt] = *(const s8v*)&LAh[buf][r * 40 + quad * 8];
      al2[mt] = *(const s8v*)&LAl[buf][r * 40 + quad * 8];
    }
#pragma unroll
    for (int ct = 0; ct < 4; ++ct) {
      int c = wc * 64 + ct * 16 + m;
      s8v bh = *(const s8v*)&LBh[buf][c * 40 + quad * 8];
      s8v bl = *(const s8v*)&LBl[buf][c * 40 + quad * 8];
#pragma unroll
      for (int mt = 0; mt < 2; ++mt) {
        acc[mt][ct] = __builtin_amdgcn_mfma_f32_16x16x32_bf16(ah[mt], bh, acc[mt][ct], 0, 0, 0);
        acc[mt][ct] = __builtin_amdgcn_mfma_f32_16x16x32_bf16(ah[mt], bl, acc[mt][ct], 0, 0, 0);
        acc[mt][ct] = __builtin_amdgcn_mfma_f32_16x16x32_bf16(al2[mt], bh, acc[mt][ct], 0, 0, 0);
      }
    }
  };

  LOADG(0, 0);
  if (nkb > 1) LOADG(1, 1);
  int kb = 0;
  for (; kb + 2 <= nkb; kb += 2) {
    WRITES(0);
    __syncthreads();
    if (kb + 2 < nkb) LOADG(0, kb + 2);
    MF(0);
    WRITES(1);
    __syncthreads();
    if (kb + 3 < nkb) LOADG(1, kb + 3);
    MF(1);
  }
  if (kb < nkb) {   // odd tail (not hit for K=64/512/768)
    WRITES(0);
    __syncthreads();
    MF(0);
  }
#undef LOADG
#undef WRITES

  float bb[4];
#pragma unroll
  for (int ct = 0; ct < 4; ++ct) bb[ct] = bv[wc * 64 + ct * 16 + m];
#pragma unroll
  for (int mt = 0; mt < 2; ++mt)
#pragma unroll
    for (int j = 0; j < 4; ++j) {
      int row = row0 + wr * 32 + mt * 16 + quad * 4 + j;
      if (row < N) {
        float* o = Out + (size_t)row * 128 + wc * 64 + m;
#pragma unroll
        for (int ct = 0; ct < 4; ++ct) {
          float vv = acc[mt][ct][j] + bb[ct];
          if (RELU) vv = fmaxf(vv, 0.f);
          o[ct * 16] = vv;
        }
      }
    }
}

// ---------------------------------------------------------------------------
// Consolidated CSR build over concatenated node space (4 relations).
__device__ __forceinline__ void rel_of(int g, int& r, int& loc, int& nb) {
  if (g < 450000) {
    if (g < 150000) { r = 0; loc = g;          nb = 0; }
    else            { r = 1; loc = g - 150000; nb = 50000; }
  } else if (g < 950000)  { r = 2; loc = g - 450000;  nb = 100000; }
  else                    { r = 3; loc = g - 950000;  nb = 200000; }
}
__global__ void histc_kernel(Ptrs4 dsts, int* __restrict__ cnt) {
  int g = blockIdx.x * 256 + threadIdx.x;
  if (g >= E_TOT) return;
  int r, loc, nb;
  rel_of(g, r, loc, nb);
  atomicAdd(&cnt[nb + dsts.p[r][loc]], 1);
}
__global__ __launch_bounds__(256) void scan1_kernel(const int* __restrict__ cnt,
                                                    int* __restrict__ excl,
                                                    int* __restrict__ partials, int Nd) {
  __shared__ int sb[256];
  int t = threadIdx.x;
  int base = blockIdx.x * 1024 + t * 4;
  int v[4];
#pragma unroll
  for (int j = 0; j < 4; ++j) v[j] = (base + j < Nd) ? cnt[base + j] : 0;
  int tot = v[0] + v[1] + v[2] + v[3];
  sb[t] = tot;
  __syncthreads();
  for (int off = 1; off < 256; off <<= 1) {
    int x = 0;
    if (t >= off) x = sb[t - off];
    __syncthreads();
    sb[t] += x;
    __syncthreads();
  }
  int ex = sb[t] - tot;
  if (t == 255) partials[blockIdx.x] = sb[t];
  int run = ex;
#pragma unroll
  for (int j = 0; j < 4; ++j) {
    if (base + j < Nd) excl[base + j] = run;
    run += v[j];
  }
}
__global__ __launch_bounds__(512) void scan2_kernel(int* __restrict__ partials, int B) {
  __shared__ int sb[512];
  int t = threadIdx.x;
  int v = (t < B) ? partials[t] : 0;
  sb[t] = v;
  __syncthreads();
  for (int off = 1; off < 512; off <<= 1) {
    int x = 0;
    if (t >= off) x = sb[t - off];
    __syncthreads();
    sb[t] += x;
    __syncthreads();
  }
  if (t < B) partials[t] = sb[t] - v;
}
__global__ void scan3_kernel(const int* __restrict__ excl, const int* __restrict__ partials,
                             int* __restrict__ rowptr, int* __restrict__ cursor) {
  int i = blockIdx.x * 256 + threadIdx.x;
  if (i < N_TOT) {
    int v = excl[i] + partials[i >> 10];
    rowptr[i] = v;
    cursor[i] = v;
  }
  if (i == 0) rowptr[N_TOT] = E_TOT;
}
__global__ void scatterc_kernel(Ptrs4 srcs, Ptrs4 dsts,
                                int* __restrict__ cursor, int* __restrict__ csrc) {
  int g = blockIdx.x * 256 + threadIdx.x;
  if (g >= E_TOT) return;
  int r, loc, nb;
  rel_of(g, r, loc, nb);
  int p = atomicAdd(&cursor[nb + dsts.p[r][loc]], 1);
  csrc[p] = srcs.p[r][loc];
}

// ---------------------------------------------------------------------------
// logits2: als_r[n][h] = H[n] . wsrcv_r[h]  for two relations at once.
__global__ __launch_bounds__(256) void logits2_kernel(const float* __restrict__ H,
                                                      const float* __restrict__ wsA,
                                                      const float* __restrict__ wsB,
                                                      float* __restrict__ alsA,
                                                      float* __restrict__ alsB, int Ns) {
  int n = blockIdx.x * 4 + (threadIdx.x >> 6);
  int lane = threadIdx.x & 63;
  if (n >= Ns) return;
  const float* hr = H + (size_t)n * 128;
  float ha = hr[lane], hb = hr[lane + 64];
  float p0 = ha * wsA[lane] + hb * wsA[lane + 64];
  float p1 = ha * wsA[128 + lane] + hb * wsA[192 + lane];
  float p2 = ha * wsB[lane] + hb * wsB[lane + 64];
  float p3 = ha * wsB[128 + lane] + hb * wsB[192 + lane];
#pragma unroll
  for (int mk = 32; mk; mk >>= 1) {
    p0 += __shfl_xor(p0, mk); p1 += __shfl_xor(p1, mk);
    p2 += __shfl_xor(p2, mk); p3 += __shfl_xor(p3, mk);
  }
  if (lane == 0) {
    *(float2*)(alsA + 2 * (size_t)n) = make_float2(p0, p1);
    *(float2*)(alsB + 2 * (size_t)n) = make_float2(p2, p3);
  }
}

// ---------------------------------------------------------------------------
// aggG2: half-wave per (dst,rel).  32 lanes hold all 128 channels (f4v each);
// edges serial with 8 in flight; den/acc fully lane-local (no shuffles in the
// edge loop).  Wave covers 2 dsts of one rel; block = 4 waves = 4 dsts x 2 rels.
// G row [relA h0|h1 | relB h0|h1], pre-split bf16 hi/lo.
__global__ __launch_bounds__(256) void aggG2_kernel(const int* __restrict__ rowA,
                                                    const int* __restrict__ rowB,
                                                    const int* __restrict__ csrc,
                                                    const float* __restrict__ alsA,
                                                    const float* __restrict__ alsB,
                                                    const float* __restrict__ wdvA,
                                                    const float* __restrict__ wdvB,
                                                    const float* __restrict__ Hs,
                                                    const float* __restrict__ Hd,
                                                    ushort_t* __restrict__ Gh,
                                                    ushort_t* __restrict__ Gl,
                                                    int Nd, int dOff) {
  int w = threadIdx.x >> 6;
  int lane = threadIdx.x & 63;
  int rel = w & 1;
  int hw = lane >> 5, s = lane & 31;
  int dl = blockIdx.x * 4 + (w >> 1) * 2 + hw;
  if (dl >= Nd) return;
  int d = dl + dOff;
  const int* rp = rel ? rowB : rowA;
  const float* als = rel ? alsB : alsA;
  const float* wdv = rel ? wdvB : wdvA;

  // t-values: 32-lane butterfly within the half-wave (masks <= 16)
  const float* hr = Hd + (size_t)d * 128;
  float t0 = 0.f, t1 = 0.f;
#pragma unroll
  for (int j = 0; j < 4; ++j) {
    float hv = hr[s + 32 * j];
    t0 += hv * wdv[s + 32 * j];
    t1 += hv * wdv[128 + s + 32 * j];
  }
#pragma unroll
  for (int mk = 16; mk; mk >>= 1) { t0 += __shfl_xor(t0, mk); t1 += __shfl_xor(t1, mk); }

  int start = rp[d], end = rp[d + 1];
  float den0 = 0.f, den1 = 0.f;
  f4v a0 = (f4v){0.f, 0.f, 0.f, 0.f}, a1 = (f4v){0.f, 0.f, 0.f, 0.f};
  if (end > start) {
    int last = end - 1;
    for (int b0 = start; b0 < end; b0 += 8) {
      int sid[8]; bool vl[8];
#pragma unroll
      for (int j = 0; j < 8; ++j) {
        int ee = b0 + j;
        vl[j] = ee < end;
        sid[j] = csrc[vl[j] ? ee : last];
      }
      float2 al[8]; f4v x[8];
#pragma unroll
      for (int j = 0; j < 8; ++j) {
        al[j] = *(const float2*)(als + 2 * (size_t)sid[j]);
        x[j] = *(const f4v*)(Hs + (size_t)sid[j] * 128 + 4 * s);
      }
#pragma unroll
      for (int j = 0; j < 8; ++j) {
        float w0 = vl[j] ? __expf(leaky(al[j].x + t0)) : 0.f;
        float w1 = vl[j] ? __expf(leaky(al[j].y + t1)) : 0.f;
        den0 += w0; den1 += w1;
#pragma unroll
        for (int q = 0; q < 4; ++q) { a0[q] += w0 * x[j][q]; a1[q] += w1 * x[j][q]; }
      }
    }
  }
  float i0 = 0.5f / (den0 + 1e-16f);
  float i1 = 0.5f / (den1 + 1e-16f);
  ushort_t* gh = Gh + (size_t)dl * 512 + rel * 256;
  ushort_t* gl = Gl + (size_t)dl * 512 + rel * 256;
  u4v g0h, g0l, g1h, g1l;
#pragma unroll
  for (int q = 0; q < 4; ++q) {
    ushort_t hh, ll;
    split_bf(a0[q] * i0, hh, ll); g0h[q] = hh; g0l[q] = ll;
    split_bf(a1[q] * i1, hh, ll); g1h[q] = hh; g1l[q] = ll;
  }
  *(u4v*)(gh + 4 * s) = g0h;
  *(u4v*)(gl + 4 * s) = g0l;
  *(u4v*)(gh + 128 + 4 * s) = g1h;
  *(u4v*)(gl + 128 + 4 * s) = g1l;
}

// ---------------------------------------------------------------------------
// classifier: out[n] = relu(H[n,:]@Wc1 + bc1) @ Wc2 + bc2.
__global__ __launch_bounds__(256) void classifier_kernel(const float* __restrict__ Hp,
                                                         const float* __restrict__ Wc1, const float* __restrict__ bc1,
                                                         const float* __restrict__ Wc2, const float* __restrict__ bc2,
                                                         float* __restrict__ out, int N) {
  __shared__ float sW[128 * 64];
  int t = threadIdx.x;
#pragma unroll
  for (int i = 0; i < 8; ++i) ((float4*)sW)[t + 256 * i] = ((const float4*)Wc1)[t + 256 * i];
  __syncthreads();
  int lane = t & 63, wv = t >> 6;
  float b = bc1[lane], w2 = Wc2[lane], b2 = bc2[0];
#pragma unroll
  for (int nn = 0; nn < 2; ++nn) {
    int n = blockIdx.x * 8 + wv * 2 + nn;
    if (n >= N) continue;
    const float* hr = Hp + (size_t)n * 128;
    float accz = b;
    for (int k = 0; k < 128; ++k) accz += hr[k] * sW[k * 64 + lane];
    float z = fmaxf(accz, 0.f) * w2;
#pragma unroll
    for (int off = 32; off; off >>= 1) z += __shfl_down(z, off);
    if (lane == 0) out[n] = z + b2;
  }
}

// ---------------------------------------------------------------------------
extern "C" void kernel_launch(void* const* d_in, const int* in_sizes, int n_in,
                              void* d_out, int out_size, void* d_ws, size_t ws_size,
                              hipStream_t stream) {
  const float* post_cls = (const float*)d_in[0];
  const float* user_x   = (const float*)d_in[1];
  const float* Wpost = (const float*)d_in[3];
  const float* bpost = (const float*)d_in[4];
  const float* Wuser = (const float*)d_in[5];
  const float* buser = (const float*)d_in[6];
  const float* gWsrc = (const float*)d_in[9];
  const float* gWdst = (const float*)d_in[10];
  const float* gasrc = (const float*)d_in[11];
  const float* gadst = (const float*)d_in[12];
  const float* gbias = (const float*)d_in[13];
  const float* Wc1 = (const float*)d_in[14];
  const float* bc1 = (const float*)d_in[15];
  const float* Wc2 = (const float*)d_in[16];
  const float* bc2 = (const float*)d_in[17];
  // relations kept: pub(18/19), rep(20/21), int(24/25), fol(26/27); con dropped (dead).
  Ptrs4 SRCS, DSTS;
  SRCS.p[0] = (const int*)d_in[18]; DSTS.p[0] = (const int*)d_in[19];
  SRCS.p[1] = (const int*)d_in[20]; DSTS.p[1] = (const int*)d_in[21];
  SRCS.p[2] = (const int*)d_in[24]; DSTS.p[2] = (const int*)d_in[25];
  SRCS.p[3] = (const int*)d_in[26]; DSTS.p[3] = (const int*)d_in[27];
  float* out = (float*)d_out;
  (void)ws_size; (void)in_sizes; (void)n_in; (void)out_size;

  // ---- workspace: floats, ints, ushorts (~218 MB)
  float* Wf = (float*)d_ws;
  size_t o = 0;
  float* WDSTV = Wf + o; o += 2560;
  float* WSRCV = Wf + o; o += 2560;
  float* BS    = Wf + o; o += 384;
  float* ALSa  = Wf + o; o += (size_t)N_USER * 2;
  float* ALSb  = Wf + o; o += (size_t)N_USER * 2;
  float* HU    = Wf + o; o += (size_t)N_USER * 128;
  float* HP    = Wf + o; o += (size_t)N_POST * 128;
  float* TMP   = Wf + o; o += (size_t)N_POST * 128;    // user chunk0 output
  int* Wi = (int*)(Wf + o);
  size_t io = 0;
  int* RP   = Wi + io; io += N_TOT + 1;
  int* CURS = Wi + io; io += N_TOT;
  int* CNT  = Wi + io; io += N_TOT;
  int* EXCL = Wi + io; io += N_TOT;
  int* PART = Wi + io; io += 512;
  int* CSRC = Wi + io; io += E_TOT;
  io = (io + 7) & ~(size_t)7;
  ushort_t* Wu = (ushort_t*)(Wi + io);
  size_t uo = 0;
  ushort_t* PWh = Wu + uo; uo += 128 * TEXT_D;
  ushort_t* PWl = Wu + uo; uo += 128 * TEXT_D;
  ushort_t* UWh = Wu + uo; uo += 128 * USER_D;
  ushort_t* UWl = Wu + uo; uo += 128 * USER_D;
  ushort_t* STh[3]; ushort_t* STl[3];
  for (int i = 0; i < 3; ++i) {
    STh[i] = Wu + uo; uo += 128 * 512;
    STl[i] = Wu + uo; uo += 128 * 512;
  }
  ushort_t* Gh = Wu + uo; uo += (size_t)N_POST * 512;   // 50k x 512 bf16-hi
  ushort_t* Gl = Wu + uo; uo += (size_t)N_POST * 512;   // 50k x 512 bf16-lo

  const int NOFF_PUB = 0, NOFF_REP = 50000, NOFF_INT = 100000, NOFF_FOL = 200000;

  // ---- consolidated CSR build (edges identical across layers)
  (void)hipMemsetAsync(CNT, 0, (size_t)N_TOT * sizeof(int), stream);
  histc_kernel<<<(E_TOT + 255) / 256, 256, 0, stream>>>(DSTS, CNT);
  int B = (N_TOT + 1023) / 1024;   // 293
  scan1_kernel<<<B, 256, 0, stream>>>(CNT, EXCL, PART, N_TOT);
  scan2_kernel<<<1, 512, 0, stream>>>(PART, B);
  scan3_kernel<<<(N_TOT + 255) / 256, 256, 0, stream>>>(EXCL, PART, RP, CURS);
  scatterc_kernel<<<(E_TOT + 255) / 256, 256, 0, stream>>>(SRCS, DSTS, CURS, CSRC);

  // ---- W preps
  wt_prep<<<dim3(3, 128), 256, 0, stream>>>(Wpost, PWh, PWl, TEXT_D, 128);
  wt_prep<<<dim3(1, 128), 256, 0, stream>>>(Wuser, UWh, UWl, USER_D, 128);
  // stacked src weights: [0]: l0 pub+rep, [1]: l0 int+fol, [2]: l1 pub+rep
  stk_prep<<<dim3(2, 128), 256, 0, stream>>>(gWsrc + (size_t)0 * 32768, gWsrc + (size_t)1 * 32768, STh[0], STl[0]);
  stk_prep<<<dim3(2, 128), 256, 0, stream>>>(gWsrc + (size_t)3 * 32768, gWsrc + (size_t)4 * 32768, STh[1], STl[1]);
  stk_prep<<<dim3(2, 128), 256, 0, stream>>>(gWsrc + (size_t)5 * 32768, gWsrc + (size_t)6 * 32768, STh[2], STl[2]);
  wvec_kernel<<<20, 128, 0, stream>>>(gWdst, gadst, WDSTV);
  wvec_kernel<<<20, 128, 0, stream>>>(gWsrc, gasrc, WSRCV);
  bias_sum<<<1, 128, 0, stream>>>(gbias, BS);

  // ---- projections (MFMA, bias fused, f32 out)
  gemm_pipe<false, false><<<(N_POST + 63) / 64, 256, 0, stream>>>(
      post_cls, nullptr, PWh, PWl, bpost, HP, N_POST, TEXT_D);
  gemm_pipe<false, false><<<(N_USER + 63) / 64, 256, 0, stream>>>(
      user_x, nullptr, UWh, UWl, buser, HU, N_USER, USER_D);

  // ---- layer 1: post  (pub + rep; src HU, dst HP in-place)
  logits2_kernel<<<(N_USER + 3) / 4, 256, 0, stream>>>(
      HU, WSRCV + 0 * 256, WSRCV + 1 * 256, ALSa, ALSb, N_USER);
  aggG2_kernel<<<(N_POST + 3) / 4, 256, 0, stream>>>(
      RP + NOFF_PUB, RP + NOFF_REP, CSRC, ALSa, ALSb,
      WDSTV + 0 * 256, WDSTV + 1 * 256, HU, HP, Gh, Gl, N_POST, 0);
  gemm_pipe<true, true><<<(N_POST + 63) / 64, 256, 0, stream>>>(
      Gh, Gl, STh[0], STl[0], BS + 0, HP, N_POST, 512);

  // ---- layer 1: user  (int + fol; src/dst HU, 2 chunks of 50k sharing G)
  logits2_kernel<<<(N_USER + 3) / 4, 256, 0, stream>>>(
      HU, WSRCV + 3 * 256, WSRCV + 4 * 256, ALSa, ALSb, N_USER);
  aggG2_kernel<<<(50000 + 3) / 4, 256, 0, stream>>>(
      RP + NOFF_INT, RP + NOFF_FOL, CSRC, ALSa, ALSb,
      WDSTV + 3 * 256, WDSTV + 4 * 256, HU, HU, Gh, Gl, 50000, 0);
  gemm_pipe<true, true><<<(50000 + 63) / 64, 256, 0, stream>>>(
      Gh, Gl, STh[1], STl[1], BS + 128, TMP, 50000, 512);
  aggG2_kernel<<<(50000 + 3) / 4, 256, 0, stream>>>(
      RP + NOFF_INT, RP + NOFF_FOL, CSRC, ALSa, ALSb,
      WDSTV + 3 * 256, WDSTV + 4 * 256, HU, HU, Gh, Gl, 50000, 50000);
  gemm_pipe<true, true><<<(50000 + 63) / 64, 256, 0, stream>>>(
      Gh, Gl, STh[1], STl[1], BS + 128, HU + (size_t)50000 * 128, 50000, 512);
  (void)hipMemcpyAsync(HU, TMP, (size_t)50000 * 128 * sizeof(float),
                       hipMemcpyDeviceToDevice, stream);

  // ---- layer 2: post only (output depends on nothing else)
  logits2_kernel<<<(N_USER + 3) / 4, 256, 0, stream>>>(
      HU, WSRCV + 5 * 256, WSRCV + 6 * 256, ALSa, ALSb, N_USER);
  aggG2_kernel<<<(N_POST + 3) / 4, 256, 0, stream>>>(
      RP + NOFF_PUB, RP + NOFF_REP, CSRC, ALSa, ALSb,
      WDSTV + 5 * 256, WDSTV + 6 * 256, HU, HP, Gh, Gl, N_POST, 0);
  gemm_pipe<true, true><<<(N_POST + 63) / 64, 256, 0, stream>>>(
      Gh, Gl, STh[2], STl[2], BS + 256, HP, N_POST, 512);

  classifier_kernel<<<(N_POST + 7) / 8, 256, 0, stream>>>(HP, Wc1, bc1, Wc2, bc2, out, N_POST);
}